// Round 12
// baseline (236.962 us; speedup 1.0000x reference)
//
#include <hip/hip_runtime.h>
#include <stdint.h>

static constexpr int EMB   = 1024;
static constexpr int HEADS = 16;
static constexpr int HD    = 64;
static constexpr int BATCH = 2;
static constexpr int SEQ   = 2048;
static constexpr int BT    = BATCH * SEQ;   // 4096 rows
static constexpr float QSC = 0.18033688011112042f;  // log2(e)/8

typedef short   short8  __attribute__((ext_vector_type(8)));
typedef float   float4v __attribute__((ext_vector_type(4)));

__device__ __forceinline__ ushort f2bf(float f) {          // RNE (epilogues)
    union { float f; uint32_t i; } v; v.f = f;
    uint32_t x = v.i;
    return (ushort)((x + 0x7FFFu + ((x >> 16) & 1u)) >> 16);
}
__device__ __forceinline__ ushort f2bf_rn(float f) {       // round-half-up, 2 VALU
    union { float f; uint32_t i; } v; v.f = f;
    return (ushort)((v.i + 0x8000u) >> 16);
}
__device__ __forceinline__ uint32_t pack2bf(float lo, float hi) {
    union { float f; uint32_t u; } a, b; a.f = lo; b.f = hi;
    uint32_t ra = a.u + 0x7FFFu + ((a.u >> 16) & 1u);
    uint32_t rb = b.u + 0x7FFFu + ((b.u >> 16) & 1u);
    return (rb & 0xFFFF0000u) | (ra >> 16);
}
__device__ __forceinline__ float fast_exp2(float x) {
#if __has_builtin(__builtin_amdgcn_exp2f)
    return __builtin_amdgcn_exp2f(x);   // raw v_exp_f32: 1 instr, -1e30 -> 0
#else
    return exp2f(x);
#endif
}

// async 16B global->LDS (DMA). LDS dest = wave-uniform base + lane*16.
__device__ __forceinline__ void async_ld16(const void* g, void* l) {
    __builtin_amdgcn_global_load_lds(
        (const __attribute__((address_space(1))) void*)g,
        (__attribute__((address_space(3))) void*)l,
        16, 0, 0);
}

// ---------------------------------------------------------------------------
// Pre-pass: convert fp32 inputs -> bf16 workspace. 8 elems/thread.
// ---------------------------------------------------------------------------
__global__ void cvt_all(const float* __restrict__ q, const float* __restrict__ k,
                        const float* __restrict__ v,
                        const float* __restrict__ wq, const float* __restrict__ wk,
                        const float* __restrict__ wv, const float* __restrict__ wo,
                        ushort* __restrict__ qb, ushort* __restrict__ kb,
                        ushort* __restrict__ vb,
                        ushort* __restrict__ wqb, ushort* __restrict__ wkb,
                        ushort* __restrict__ wvb, ushort* __restrict__ wob)
{
    int bid = blockIdx.x;
    const float* src; ushort* dst; size_t off;
    if (bid < 6144) {
        int seg = bid >> 11;
        src = seg == 0 ? q : (seg == 1 ? k : v);
        dst = seg == 0 ? qb : (seg == 1 ? kb : vb);
        off = (size_t)(bid & 2047) * 2048;
    } else {
        int t = bid - 6144, seg = t >> 9;
        src = seg == 0 ? wq : (seg == 1 ? wk : (seg == 2 ? wv : wo));
        dst = seg == 0 ? wqb : (seg == 1 ? wkb : (seg == 2 ? wvb : wob));
        off = (size_t)(t & 511) * 2048;
    }
    size_t base = off + (size_t)threadIdx.x * 8;
    float4 a0 = *(const float4*)(src + base);
    float4 a1 = *(const float4*)(src + base + 4);
    uint32_t o[4] = { pack2bf(a0.x, a0.y), pack2bf(a0.z, a0.w),
                      pack2bf(a1.x, a1.y), pack2bf(a1.z, a1.w) };
    *(uint4*)(dst + base) = *(uint4*)o;
}

// ---------------------------------------------------------------------------
// Core 128x128 GEMM tile, v11: PIPELINED (attn-proven transform). Double-
// buffered LDS; STAGE(k+1) issued BEFORE computing k; single vmcnt(0)+barrier
// at the bottom lands after a full 32-MFMA compute phase of cover. Swizzled
// global_load_lds staging: LDS(rowgroup, lane) holds global chunk
// (lane&7)^(row&7) so b128 fragment reads are 2-way (free) at worst.
// ---------------------------------------------------------------------------
__device__ __forceinline__ void gemm_core_128_pipe(
    const ushort* __restrict__ A, const ushort* __restrict__ W,
    int m0, int n0, int K,
    ushort (*As)[128 * 64], ushort (*Ws)[128 * 64],
    int wid, int lane, float4v acc[4][4])
{
    const int lrow8 = lane >> 3;
    const int gc    = (lane & 7) ^ lrow8;
    const ushort* Ab = A + (size_t)m0 * K + gc * 8;
    const ushort* Wb = W + (size_t)n0 * K + gc * 8;
    const int wm = (wid >> 1) * 64;
    const int wn = (wid & 1) * 64;

#define GSTAGE(k0, sel)                                                        \
    {                                                                          \
        _Pragma("unroll")                                                      \
        for (int it = 0; it < 4; ++it) {                                       \
            int rg = it * 4 + wid;               /* row group 0..15 */         \
            int row = rg * 8 + lrow8;                                          \
            async_ld16(Ab + (size_t)row * K + (k0), &As[sel][rg * 512]);       \
            async_ld16(Wb + (size_t)row * K + (k0), &Ws[sel][rg * 512]);       \
        }                                                                      \
    }

    GSTAGE(0, 0);
    asm volatile("s_waitcnt vmcnt(0)" ::: "memory");
    __syncthreads();

    int cur = 0;
    for (int k0 = 0; k0 < K; k0 += 64) {
        if (k0 + 64 < K) GSTAGE(k0 + 64, cur ^ 1);

        const ushort* Ac = As[cur];
        const ushort* Wc = Ws[cur];
        __builtin_amdgcn_s_setprio(1);
#pragma unroll
        for (int ks = 0; ks < 2; ++ks) {
            const int c = ks * 4 + (lane >> 4);
            short8 af[4], wf[4];
#pragma unroll
            for (int i = 0; i < 4; i++) {
                int row = wm + i * 16 + (lane & 15);
                af[i] = *(const short8*)&Ac[row * 64 + ((c ^ (row & 7)) * 8)];
            }
#pragma unroll
            for (int j = 0; j < 4; j++) {
                int row = wn + j * 16 + (lane & 15);
                wf[j] = *(const short8*)&Wc[row * 64 + ((c ^ (row & 7)) * 8)];
            }
#pragma unroll
            for (int i = 0; i < 4; i++)
#pragma unroll
                for (int j = 0; j < 4; j++)
                    acc[i][j] = __builtin_amdgcn_mfma_f32_16x16x32_bf16(af[i], wf[j], acc[i][j], 0, 0, 0);
        }
        __builtin_amdgcn_s_setprio(0);

        asm volatile("s_waitcnt vmcnt(0)" ::: "memory");
        __syncthreads();
        cur ^= 1;
    }
#undef GSTAGE
}

// ---------------------------------------------------------------------------
// Fused Q/K/V projection GEMM: blockIdx.z selects {Q,K,V}.
// v11: pipelined core, dbuf LDS = 64 KB -> 2 blocks/CU (was 3 with drain).
// v4's lesson: pipeline + 2 blocks beats drain + 3 blocks at 32 MFMA/iter.
// ---------------------------------------------------------------------------
__global__ __launch_bounds__(256, 2)
void gemm_qkv(const ushort* __restrict__ qb, const ushort* __restrict__ kb,
              const ushort* __restrict__ vb,
              const ushort* __restrict__ wqb, const ushort* __restrict__ wkb,
              const ushort* __restrict__ wvb,
              const float* __restrict__ bq, const float* __restrict__ bk,
              const float* __restrict__ bv,
              const float* __restrict__ cbq, const float* __restrict__ cbk,
              ushort* __restrict__ qc, ushort* __restrict__ kc,
              ushort* __restrict__ vt)
{
    __shared__ __align__(16) ushort As[2][128 * 64];
    __shared__ __align__(16) ushort Ws[2][128 * 64];

    const int z = blockIdx.z;
    const ushort* A    = z == 0 ? qb  : (z == 1 ? kb  : vb);
    const ushort* W    = z == 0 ? wqb : (z == 1 ? wkb : wvb);
    const float*  bias = z == 0 ? bq  : (z == 1 ? bk  : bv);
    const float*  clrb = z == 0 ? cbq : cbk;
    const float   scale = z == 0 ? QSC : 1.0f;

    const int tid  = threadIdx.x;
    const int wid  = tid >> 6;
    const int lane = tid & 63;
    const int m0 = blockIdx.y * 128;
    const int n0 = blockIdx.x * 128;
    const int wm = (wid >> 1) * 64;
    const int wn = (wid & 1) * 64;

    float4v acc[4][4];
#pragma unroll
    for (int i = 0; i < 4; i++)
#pragma unroll
        for (int j = 0; j < 4; j++) acc[i][j] = (float4v)0.0f;

    gemm_core_128_pipe(A, W, m0, n0, EMB, As, Ws, wid, lane, acc);

    // Epilogue. C/D: col=lane&15, row=(lane>>4)*4+reg  [m89]
    const int h = (n0 + wn) >> 6;   // head (64 cols == wave n-tile)
#pragma unroll
    for (int i = 0; i < 4; i++) {
        float ys[4][4];
#pragma unroll
        for (int j = 0; j < 4; j++) {
            float bj = bias[n0 + wn + j * 16 + (lane & 15)];
#pragma unroll
            for (int r = 0; r < 4; r++) ys[j][r] = acc[i][j][r] + bj;
        }
        const int rowb = m0 + wm + i * 16 + ((lane >> 4) << 2);

        if (z < 2) {
            float rs[4];
#pragma unroll
            for (int r = 0; r < 4; r++)
                rs[r] = ys[0][r] + ys[1][r] + ys[2][r] + ys[3][r];
#pragma unroll
            for (int r = 0; r < 4; r++)
#pragma unroll
                for (int off = 1; off < 16; off <<= 1)
                    rs[r] += __shfl_xor(rs[r], off, 64);
            ushort* Yb = z == 0 ? qc : kc;
#pragma unroll
            for (int j = 0; j < 4; j++) {
                int d = j * 16 + (lane & 15);
                float cb = clrb[h * HD + d];
#pragma unroll
                for (int r = 0; r < 4; r++) {
                    int row = rowb + r;
                    int b = row >> 11, t = row & (SEQ - 1);
                    Yb[((size_t)(b * HEADS + h) * SEQ + t) * HD + d] =
                        f2bf((ys[j][r] - rs[r] * (1.0f / 64.0f) + cb) * scale);
                }
            }
        } else {
#pragma unroll
            for (int j = 0; j < 4; j++) {
                int d = j * 16 + (lane & 15);
#pragma unroll
                for (int r = 0; r < 4; r++) {
                    int row = rowb + r;
                    int b = row >> 11, t = row & (SEQ - 1);
                    vt[((size_t)(b * HEADS + h) * HD + d) * SEQ + t] = f2bf(ys[j][r]);
                }
            }
        }
    }
}

// ---------------------------------------------------------------------------
// Output projection GEMM: fp32 row-major output. 64x64 tiles.
// v11: pipelined + dbuf (32 KB LDS) -> 4 blocks/CU PRESERVED + prefetch.
// ---------------------------------------------------------------------------
__global__ __launch_bounds__(256, 4)
void gemm_out(const ushort* __restrict__ A, const ushort* __restrict__ W,
              const float* __restrict__ bias, float* __restrict__ Y)
{
    __shared__ __align__(16) ushort As[2][64 * 64];
    __shared__ __align__(16) ushort Ws[2][64 * 64];

    const int tid  = threadIdx.x;
    const int wid  = tid >> 6;
    const int lane = tid & 63;
    const int m0 = blockIdx.y * 64;
    const int n0 = blockIdx.x * 64;
    const int wm = (wid >> 1) * 32;
    const int wn = (wid & 1) * 32;

    const int lrow8 = lane >> 3;
    const int gc    = (lane & 7) ^ lrow8;
    const ushort* Ab = A + (size_t)m0 * EMB + gc * 8;
    const ushort* Wb = W + (size_t)n0 * EMB + gc * 8;

    float4v acc[2][2];
#pragma unroll
    for (int i = 0; i < 2; i++)
#pragma unroll
        for (int j = 0; j < 2; j++) acc[i][j] = (float4v)0.0f;

#define OSTAGE(k0, sel)                                                        \
    {                                                                          \
        _Pragma("unroll")                                                      \
        for (int it = 0; it < 2; ++it) {                                       \
            int rg = it * 4 + wid;               /* row group 0..7 */          \
            int row = rg * 8 + lrow8;                                          \
            async_ld16(Ab + (size_t)row * EMB + (k0), &As[sel][rg * 512]);     \
            async_ld16(Wb + (size_t)row * EMB + (k0), &Ws[sel][rg * 512]);     \
        }                                                                      \
    }

    OSTAGE(0, 0);
    asm volatile("s_waitcnt vmcnt(0)" ::: "memory");
    __syncthreads();

    int cur = 0;
    for (int k0 = 0; k0 < EMB; k0 += 64) {
        if (k0 + 64 < EMB) OSTAGE(k0 + 64, cur ^ 1);

        const ushort* Ac = As[cur];
        const ushort* Wc = Ws[cur];
        __builtin_amdgcn_s_setprio(1);
#pragma unroll
        for (int ks = 0; ks < 2; ++ks) {
            const int c = ks * 4 + (lane >> 4);
            short8 af[2], wf[2];
#pragma unroll
            for (int i = 0; i < 2; i++) {
                int row = wm + i * 16 + (lane & 15);
                af[i] = *(const short8*)&Ac[row * 64 + ((c ^ (row & 7)) * 8)];
            }
#pragma unroll
            for (int j = 0; j < 2; j++) {
                int row = wn + j * 16 + (lane & 15);
                wf[j] = *(const short8*)&Wc[row * 64 + ((c ^ (row & 7)) * 8)];
            }
#pragma unroll
            for (int i = 0; i < 2; i++)
#pragma unroll
                for (int j = 0; j < 2; j++)
                    acc[i][j] = __builtin_amdgcn_mfma_f32_16x16x32_bf16(af[i], wf[j], acc[i][j], 0, 0, 0);
        }
        __builtin_amdgcn_s_setprio(0);

        asm volatile("s_waitcnt vmcnt(0)" ::: "memory");
        __syncthreads();
        cur ^= 1;
    }
#undef OSTAGE

#pragma unroll
    for (int i = 0; i < 2; i++) {
        const int rowb = m0 + wm + i * 16 + ((lane >> 4) << 2);
#pragma unroll
        for (int j = 0; j < 2; j++) {
            int col = n0 + wn + j * 16 + (lane & 15);
            float bj = bias[col];
#pragma unroll
            for (int r = 0; r < 4; r++)
                Y[(size_t)(rowb + r) * EMB + col] = acc[i][j][r] + bj;
        }
    }
}

// ---------------------------------------------------------------------------
// Flash attention, static softmax (scores provably small; Q pre-scaled by
// log2(e)/8 -> p=exp2(s), m==0). Per (b,h,128-q-tile), KVBLK=64 dbuf.
// v10 structure unchanged (best measured: 63.9 µs): 8 waves x 16 q-rows,
// mask-in-registers (vmcnt-clean prefetch in the STAGE window), LDS 51200 B.
// ---------------------------------------------------------------------------
__global__ __launch_bounds__(512, 4)
void attn_kernel(const ushort* __restrict__ qc,
                 const ushort* __restrict__ kc,
                 const ushort* __restrict__ vt,
                 const unsigned char* __restrict__ mask,
                 ushort* __restrict__ out)
{
    __shared__ __align__(16) ushort Ks[2][64 * 64];
    __shared__ __align__(16) ushort Vs[2][64 * 64];
    __shared__ __align__(16) ushort Ps[8][16 * 72];

    const int tid  = threadIdx.x;
    const int wid  = tid >> 6;        // 0..7
    const int lane = tid & 63;
    const int c    = lane & 15;
    const int hi   = lane >> 4;

    const int bid = blockIdx.x;
    const int qt = bid & 15;          // 16 q-tiles of 128 rows
    const int h  = (bid >> 4) & 15;
    const int b  = bid >> 8;

    const ushort* qbase = qc + ((size_t)(b * HEADS + h)) * SEQ * HD;
    const ushort* kbase = kc + ((size_t)(b * HEADS + h)) * SEQ * HD;
    const ushort* vbase = vt + ((size_t)(b * HEADS + h)) * HD * SEQ;
    const unsigned char* mbase = mask + b * SEQ;

    // ---- Q fragments (global loads precede STAGE; drained by prologue wait)
    const int qrow = qt * 128 + wid * 16 + c;
    short8 qf[2];
#pragma unroll
    for (int ks = 0; ks < 2; ++ks)
        qf[ks] = *(const short8*)(qbase + (size_t)qrow * HD + ks * 32 + hi * 8);

    float l_r[4] = {0.f, 0.f, 0.f, 0.f};
    float4v o[4];
#pragma unroll
    for (int j = 0; j < 4; j++) o[j] = (float4v)0.f;

    const int lrow8 = lane >> 3;
    const int gc    = (lane & 7) ^ lrow8;   // pre-swizzled global chunk
    ushort* Pw = &Ps[wid][0];

    // ---- stage K/V tile t into buffer sel: wave w stages 8-row group w.
#define STAGE(t, sel)                                                          \
    {                                                                          \
        int row = wid * 8 + lrow8;                                             \
        async_ld16(kbase + (size_t)((t) * 64 + row) * HD + gc * 8,             \
                   &Ks[sel][wid * 512]);                                       \
        async_ld16(vbase + (size_t)row * SEQ + (t) * 64 + gc * 8,              \
                   &Vs[sel][wid * 512]);                                       \
    }

    // prologue: mask bytes for tile 0 + stage tile 0
    uint32_t mcur[4], mnext[4];
#pragma unroll
    for (int j = 0; j < 4; ++j)
        mcur[j] = mbase[j * 16 + c];
    STAGE(0, 0);
    asm volatile("s_waitcnt vmcnt(0)" ::: "memory");
    __syncthreads();

    int cur = 0;
    for (int kt = 0; kt < SEQ / 64; ++kt) {
        // issue next tile's DMA + next tile's mask bytes — all fly during
        // this tile's compute; drained together at the bottom vmcnt(0).
        if (kt + 1 < SEQ / 64) STAGE(kt + 1, cur ^ 1);
        const int tn = (kt + 1 < SEQ / 64) ? kt + 1 : kt;   // clamped
#pragma unroll
        for (int j = 0; j < 4; ++j)
            mnext[j] = mbase[tn * 64 + j * 16 + c];

        const ushort* Kc = &Ks[cur][0];
        const ushort* Vc = &Vs[cur][0];

        // mask additive terms from the regs prefetched LAST iteration
        float mzv[4];
#pragma unroll
        for (int j = 0; j < 4; ++j)
            mzv[j] = mcur[j] ? -1e30f : 0.0f;

        float4v s[4];
        __builtin_amdgcn_s_setprio(1);
#pragma unroll
        for (int j = 0; j < 4; j++) {
            s[j] = (float4v)0.f;
#pragma unroll
            for (int ks = 0; ks < 2; ks++) {
                int row = j * 16 + c;
                int cc  = ks * 4 + hi;
                short8 kf = *(const short8*)&Kc[row * 64 + ((cc ^ (row & 7)) * 8)];
                s[j] = __builtin_amdgcn_mfma_f32_16x16x32_bf16(qf[ks], kf, s[j], 0, 0, 0);
            }
        }
        __builtin_amdgcn_s_setprio(0);

        // exp2 -> accumulate l, write P (C-layout -> A-layout via LDS)
#pragma unroll
        for (int j = 0; j < 4; j++) {
            int prow = (hi << 2) * 72 + j * 16 + c;
#pragma unroll
            for (int r = 0; r < 4; r++) {
                float p = fast_exp2(s[j][r] + mzv[j]);   // 1 add + 1 v_exp
                l_r[r] += p;
                Pw[prow + r * 72] = f2bf_rn(p);          // 2 VALU
            }
        }
        asm volatile("s_waitcnt lgkmcnt(0)" ::: "memory");   // wave-private RAW

        short8 pf[2];
#pragma unroll
        for (int ks = 0; ks < 2; ks++)
            pf[ks] = *(const short8*)&Pw[c * 72 + ks * 32 + hi * 8];

        __builtin_amdgcn_s_setprio(1);
#pragma unroll
        for (int j = 0; j < 4; j++) {
            int d = j * 16 + c;
#pragma unroll
            for (int ks = 0; ks < 2; ks++) {
                int cc = ks * 4 + hi;
                short8 vf = *(const short8*)&Vc[d * 64 + ((cc ^ (d & 7)) * 8)];
                o[j] = __builtin_amdgcn_mfma_f32_16x16x32_bf16(pf[ks], vf, o[j], 0, 0, 0);
            }
        }
        __builtin_amdgcn_s_setprio(0);

        // end of tile: next tile's DMA + mask bytes (issued at top) drain
        // here, after a full compute phase of cover.
        asm volatile("s_waitcnt vmcnt(0)" ::: "memory");
        __syncthreads();
        cur ^= 1;
#pragma unroll
        for (int j = 0; j < 4; ++j)
            mcur[j] = mnext[j];
    }
#undef STAGE

#pragma unroll
    for (int r = 0; r < 4; r++)
#pragma unroll
        for (int off = 1; off < 16; off <<= 1)
            l_r[r] += __shfl_xor(l_r[r], off, 64);

    const int qrow_out = qt * 128 + wid * 16 + (hi << 2);
#pragma unroll
    for (int j = 0; j < 4; j++) {
        int d = j * 16 + c;
#pragma unroll
        for (int r = 0; r < 4; r++) {
            float val = o[j][r] / l_r[r];
            out[((size_t)(b * SEQ + qrow_out + r)) * EMB + h * HD + d] = f2bf(val);
        }
    }
}

// ---------------------------------------------------------------------------
extern "C" void kernel_launch(void* const* d_in, const int* in_sizes, int n_in,
                              void* d_out, int out_size, void* d_ws, size_t ws_size,
                              hipStream_t stream)
{
    const float* query = (const float*)d_in[0];
    const float* key_  = (const float*)d_in[1];
    const float* value = (const float*)d_in[2];
    const unsigned char* mask = (const unsigned char*)d_in[3];
    const float* Wq  = (const float*)d_in[4];
    const float* bq  = (const float*)d_in[5];
    const float* Wk  = (const float*)d_in[6];
    const float* bk  = (const float*)d_in[7];
    const float* Wv  = (const float*)d_in[8];
    const float* bv  = (const float*)d_in[9];
    const float* Wo  = (const float*)d_in[10];
    const float* bo  = (const float*)d_in[11];
    const float* cbq = (const float*)d_in[12];
    const float* cbk = (const float*)d_in[13];

    ushort* ws = (ushort*)d_ws;
    const size_t n1 = (size_t)BT * EMB;   // 4M elems
    const size_t nw = (size_t)EMB * EMB;  // 1M elems
    ushort* qb  = ws;
    ushort* kb  = qb  + n1;
    ushort* vb  = kb  + n1;
    ushort* wqb = vb  + n1;
    ushort* wkb = wqb + nw;
    ushort* wvb = wkb + nw;
    ushort* wob = wvb + nw;
    ushort* qc  = wob + nw;           // (B,H,T,D) centered, *log2e/8
    ushort* kc  = qc  + n1;           // (B,H,T,D) centered
    ushort* vt  = kc  + n1;           // (B,H,D,T)
    ushort* ao  = qb;                 // reuse qb slot (stream-serialized)

    cvt_all<<<8192, 256, 0, stream>>>(query, key_, value, Wq, Wk, Wv, Wo,
                                      qb, kb, vb, wqb, wkb, wvb, wob);

    dim3 gq(EMB / 128, BT / 128, 3);
    gemm_qkv<<<gq, 256, 0, stream>>>(qb, kb, vb, wqb, wkb, wvb,
                                     bq, bk, bv, cbq, cbk, qc, kc, vt);

    attn_kernel<<<BATCH * HEADS * (SEQ / 128), 512, 0, stream>>>(qc, kc, vt, mask, ao);

    dim3 go(EMB / 64, BT / 64);
    gemm_out<<<go, 256, 0, stream>>>(ao, wob, bo, (float*)d_out);
}

// Round 13
// 232.883 us; speedup vs baseline: 1.0175x; 1.0175x over previous
//
#include <hip/hip_runtime.h>
#include <stdint.h>

static constexpr int EMB   = 1024;
static constexpr int HEADS = 16;
static constexpr int HD    = 64;
static constexpr int BATCH = 2;
static constexpr int SEQ   = 2048;
static constexpr int BT    = BATCH * SEQ;   // 4096 rows
static constexpr float QSC = 0.18033688011112042f;  // log2(e)/8

typedef short   short8  __attribute__((ext_vector_type(8)));
typedef float   float4v __attribute__((ext_vector_type(4)));

__device__ __forceinline__ ushort f2bf(float f) {          // RNE (epilogues)
    union { float f; uint32_t i; } v; v.f = f;
    uint32_t x = v.i;
    return (ushort)((x + 0x7FFFu + ((x >> 16) & 1u)) >> 16);
}
__device__ __forceinline__ ushort f2bf_rn(float f) {       // round-half-up, 2 VALU
    union { float f; uint32_t i; } v; v.f = f;
    return (ushort)((v.i + 0x8000u) >> 16);
}
__device__ __forceinline__ uint32_t pack2bf(float lo, float hi) {
    union { float f; uint32_t u; } a, b; a.f = lo; b.f = hi;
    uint32_t ra = a.u + 0x7FFFu + ((a.u >> 16) & 1u);
    uint32_t rb = b.u + 0x7FFFu + ((b.u >> 16) & 1u);
    return (rb & 0xFFFF0000u) | (ra >> 16);
}
__device__ __forceinline__ float fast_exp2(float x) {
#if __has_builtin(__builtin_amdgcn_exp2f)
    return __builtin_amdgcn_exp2f(x);   // raw v_exp_f32: 1 instr, -1e30 -> 0
#else
    return exp2f(x);
#endif
}

// async 16B global->LDS (DMA). LDS dest = wave-uniform base + lane*16.
__device__ __forceinline__ void async_ld16(const void* g, void* l) {
    __builtin_amdgcn_global_load_lds(
        (const __attribute__((address_space(1))) void*)g,
        (__attribute__((address_space(3))) void*)l,
        16, 0, 0);
}

// ---------------------------------------------------------------------------
// Pre-pass: convert fp32 inputs -> bf16 workspace. 8 elems/thread.
// ---------------------------------------------------------------------------
__global__ void cvt_all(const float* __restrict__ q, const float* __restrict__ k,
                        const float* __restrict__ v,
                        const float* __restrict__ wq, const float* __restrict__ wk,
                        const float* __restrict__ wv, const float* __restrict__ wo,
                        ushort* __restrict__ qb, ushort* __restrict__ kb,
                        ushort* __restrict__ vb,
                        ushort* __restrict__ wqb, ushort* __restrict__ wkb,
                        ushort* __restrict__ wvb, ushort* __restrict__ wob)
{
    int bid = blockIdx.x;
    const float* src; ushort* dst; size_t off;
    if (bid < 6144) {
        int seg = bid >> 11;
        src = seg == 0 ? q : (seg == 1 ? k : v);
        dst = seg == 0 ? qb : (seg == 1 ? kb : vb);
        off = (size_t)(bid & 2047) * 2048;
    } else {
        int t = bid - 6144, seg = t >> 9;
        src = seg == 0 ? wq : (seg == 1 ? wk : (seg == 2 ? wv : wo));
        dst = seg == 0 ? wqb : (seg == 1 ? wkb : (seg == 2 ? wvb : wob));
        off = (size_t)(t & 511) * 2048;
    }
    size_t base = off + (size_t)threadIdx.x * 8;
    float4 a0 = *(const float4*)(src + base);
    float4 a1 = *(const float4*)(src + base + 4);
    uint32_t o[4] = { pack2bf(a0.x, a0.y), pack2bf(a0.z, a0.w),
                      pack2bf(a1.x, a1.y), pack2bf(a1.z, a1.w) };
    *(uint4*)(dst + base) = *(uint4*)o;
}

// ---------------------------------------------------------------------------
// Core 128x128 GEMM tile (m97 structure): 4 waves, each 64x64 = 4x4 MFMA acc.
// DRAIN staging (round-12 A/B: at 3 blocks/CU the implicit wave-level overlap
// of 12 waves/CU already hides the barrier drain; pipelined dbuf at
// 2 blocks/CU measured WORSE — occupancy beats prefetch in this kernel).
// Swizzled global_load_lds: LDS(rowgroup, lane) holds chunk (lane&7)^(row&7).
// ---------------------------------------------------------------------------
__device__ __forceinline__ void gemm_core_128(
    const ushort* __restrict__ A, const ushort* __restrict__ W,
    int m0, int n0, int K,
    ushort* As, ushort* Ws,
    int wid, int lane, float4v acc[4][4])
{
    const int lrow8 = lane >> 3;
    const int gc    = (lane & 7) ^ lrow8;
    const ushort* Ab = A + (size_t)m0 * K + gc * 8;
    const ushort* Wb = W + (size_t)n0 * K + gc * 8;
    const int wm = (wid >> 1) * 64;
    const int wn = (wid & 1) * 64;

    for (int k0 = 0; k0 < K; k0 += 64) {
        __syncthreads();
#pragma unroll
        for (int it = 0; it < 4; ++it) {
            int rg = it * 4 + wid;               // row group 0..15 (8 rows each)
            int row = rg * 8 + lrow8;
            async_ld16(Ab + (size_t)row * K + k0, &As[rg * 512]);
            async_ld16(Wb + (size_t)row * K + k0, &Ws[rg * 512]);
        }
        __syncthreads();
#pragma unroll
        for (int ks = 0; ks < 2; ++ks) {
            const int c = ks * 4 + (lane >> 4);
            short8 af[4], wf[4];
#pragma unroll
            for (int i = 0; i < 4; i++) {
                int row = wm + i * 16 + (lane & 15);
                af[i] = *(const short8*)&As[row * 64 + ((c ^ (row & 7)) * 8)];
            }
#pragma unroll
            for (int j = 0; j < 4; j++) {
                int row = wn + j * 16 + (lane & 15);
                wf[j] = *(const short8*)&Ws[row * 64 + ((c ^ (row & 7)) * 8)];
            }
#pragma unroll
            for (int i = 0; i < 4; i++)
#pragma unroll
                for (int j = 0; j < 4; j++)
                    acc[i][j] = __builtin_amdgcn_mfma_f32_16x16x32_bf16(af[i], wf[j], acc[i][j], 0, 0, 0);
        }
    }
}

// ---------------------------------------------------------------------------
// Fused Q/K/V projection GEMM: blockIdx.z selects {Q,K,V}. Drain core,
// 32 KB LDS -> 3 blocks/CU (round-12 A/B winner).
// ---------------------------------------------------------------------------
__global__ __launch_bounds__(256, 3)
void gemm_qkv(const ushort* __restrict__ qb, const ushort* __restrict__ kb,
              const ushort* __restrict__ vb,
              const ushort* __restrict__ wqb, const ushort* __restrict__ wkb,
              const ushort* __restrict__ wvb,
              const float* __restrict__ bq, const float* __restrict__ bk,
              const float* __restrict__ bv,
              const float* __restrict__ cbq, const float* __restrict__ cbk,
              ushort* __restrict__ qc, ushort* __restrict__ kc,
              ushort* __restrict__ vt)
{
    __shared__ __align__(16) ushort As[128 * 64];
    __shared__ __align__(16) ushort Ws[128 * 64];

    const int z = blockIdx.z;
    const ushort* A    = z == 0 ? qb  : (z == 1 ? kb  : vb);
    const ushort* W    = z == 0 ? wqb : (z == 1 ? wkb : wvb);
    const float*  bias = z == 0 ? bq  : (z == 1 ? bk  : bv);
    const float*  clrb = z == 0 ? cbq : cbk;
    const float   scale = z == 0 ? QSC : 1.0f;

    const int tid  = threadIdx.x;
    const int wid  = tid >> 6;
    const int lane = tid & 63;
    const int m0 = blockIdx.y * 128;
    const int n0 = blockIdx.x * 128;
    const int wm = (wid >> 1) * 64;
    const int wn = (wid & 1) * 64;

    float4v acc[4][4];
#pragma unroll
    for (int i = 0; i < 4; i++)
#pragma unroll
        for (int j = 0; j < 4; j++) acc[i][j] = (float4v)0.0f;

    gemm_core_128(A, W, m0, n0, EMB, As, Ws, wid, lane, acc);

    // Epilogue. C/D: col=lane&15, row=(lane>>4)*4+reg  [m89]
    const int h = (n0 + wn) >> 6;   // head (64 cols == wave n-tile)
#pragma unroll
    for (int i = 0; i < 4; i++) {
        float ys[4][4];
#pragma unroll
        for (int j = 0; j < 4; j++) {
            float bj = bias[n0 + wn + j * 16 + (lane & 15)];
#pragma unroll
            for (int r = 0; r < 4; r++) ys[j][r] = acc[i][j][r] + bj;
        }
        const int rowb = m0 + wm + i * 16 + ((lane >> 4) << 2);

        if (z < 2) {
            float rs[4];
#pragma unroll
            for (int r = 0; r < 4; r++)
                rs[r] = ys[0][r] + ys[1][r] + ys[2][r] + ys[3][r];
#pragma unroll
            for (int r = 0; r < 4; r++)
#pragma unroll
                for (int off = 1; off < 16; off <<= 1)
                    rs[r] += __shfl_xor(rs[r], off, 64);
            ushort* Yb = z == 0 ? qc : kc;
#pragma unroll
            for (int j = 0; j < 4; j++) {
                int d = j * 16 + (lane & 15);
                float cb = clrb[h * HD + d];
#pragma unroll
                for (int r = 0; r < 4; r++) {
                    int row = rowb + r;
                    int b = row >> 11, t = row & (SEQ - 1);
                    Yb[((size_t)(b * HEADS + h) * SEQ + t) * HD + d] =
                        f2bf((ys[j][r] - rs[r] * (1.0f / 64.0f) + cb) * scale);
                }
            }
        } else {
#pragma unroll
            for (int j = 0; j < 4; j++) {
                int d = j * 16 + (lane & 15);
#pragma unroll
                for (int r = 0; r < 4; r++) {
                    int row = rowb + r;
                    int b = row >> 11, t = row & (SEQ - 1);
                    vt[((size_t)(b * HEADS + h) * HD + d) * SEQ + t] = f2bf(ys[j][r]);
                }
            }
        }
    }
}

// ---------------------------------------------------------------------------
// Output projection GEMM: fp32 row-major output. 64x64 tiles.
// Pipelined + dbuf (32 KB LDS) -> 4 blocks/CU PRESERVED + prefetch (kept
// from round 12; this round's total vs round 11 measures its Δ directly).
// ---------------------------------------------------------------------------
__global__ __launch_bounds__(256, 4)
void gemm_out(const ushort* __restrict__ A, const ushort* __restrict__ W,
              const float* __restrict__ bias, float* __restrict__ Y)
{
    __shared__ __align__(16) ushort As[2][64 * 64];
    __shared__ __align__(16) ushort Ws[2][64 * 64];

    const int tid  = threadIdx.x;
    const int wid  = tid >> 6;
    const int lane = tid & 63;
    const int m0 = blockIdx.y * 64;
    const int n0 = blockIdx.x * 64;
    const int wm = (wid >> 1) * 32;
    const int wn = (wid & 1) * 32;

    const int lrow8 = lane >> 3;
    const int gc    = (lane & 7) ^ lrow8;
    const ushort* Ab = A + (size_t)m0 * EMB + gc * 8;
    const ushort* Wb = W + (size_t)n0 * EMB + gc * 8;

    float4v acc[2][2];
#pragma unroll
    for (int i = 0; i < 2; i++)
#pragma unroll
        for (int j = 0; j < 2; j++) acc[i][j] = (float4v)0.0f;

#define OSTAGE(k0, sel)                                                        \
    {                                                                          \
        _Pragma("unroll")                                                      \
        for (int it = 0; it < 2; ++it) {                                       \
            int rg = it * 4 + wid;               /* row group 0..7 */          \
            int row = rg * 8 + lrow8;                                          \
            async_ld16(Ab + (size_t)row * EMB + (k0), &As[sel][rg * 512]);     \
            async_ld16(Wb + (size_t)row * EMB + (k0), &Ws[sel][rg * 512]);     \
        }                                                                      \
    }

    OSTAGE(0, 0);
    asm volatile("s_waitcnt vmcnt(0)" ::: "memory");
    __syncthreads();

    int cur = 0;
    for (int k0 = 0; k0 < EMB; k0 += 64) {
        if (k0 + 64 < EMB) OSTAGE(k0 + 64, cur ^ 1);

        const ushort* Ac = As[cur];
        const ushort* Wc = Ws[cur];
        __builtin_amdgcn_s_setprio(1);
#pragma unroll
        for (int ks = 0; ks < 2; ++ks) {
            const int c = ks * 4 + (lane >> 4);
            short8 af[2], wf[2];
#pragma unroll
            for (int i = 0; i < 2; i++) {
                int row = wm + i * 16 + (lane & 15);
                af[i] = *(const short8*)&Ac[row * 64 + ((c ^ (row & 7)) * 8)];
            }
#pragma unroll
            for (int j = 0; j < 2; j++) {
                int row = wn + j * 16 + (lane & 15);
                wf[j] = *(const short8*)&Wc[row * 64 + ((c ^ (row & 7)) * 8)];
            }
#pragma unroll
            for (int i = 0; i < 2; i++)
#pragma unroll
                for (int j = 0; j < 2; j++)
                    acc[i][j] = __builtin_amdgcn_mfma_f32_16x16x32_bf16(af[i], wf[j], acc[i][j], 0, 0, 0);
        }
        __builtin_amdgcn_s_setprio(0);

        asm volatile("s_waitcnt vmcnt(0)" ::: "memory");
        __syncthreads();
        cur ^= 1;
    }
#undef OSTAGE

#pragma unroll
    for (int i = 0; i < 2; i++) {
        const int rowb = m0 + wm + i * 16 + ((lane >> 4) << 2);
#pragma unroll
        for (int j = 0; j < 2; j++) {
            int col = n0 + wn + j * 16 + (lane & 15);
            float bj = bias[col];
#pragma unroll
            for (int r = 0; r < 4; r++)
                Y[(size_t)(rowb + r) * EMB + col] = acc[i][j][r] + bj;
        }
    }
}

// ---------------------------------------------------------------------------
// Flash attention, static softmax (scores provably small; Q pre-scaled by
// log2(e)/8 -> p=exp2(s), m==0). Per (b,h,128-q-tile), KVBLK=64 dbuf.
// v10 structure unchanged (best measured: 63.9 µs): 8 waves x 16 q-rows,
// mask-in-registers (vmcnt-clean prefetch in the STAGE window), LDS 51200 B.
// ---------------------------------------------------------------------------
__global__ __launch_bounds__(512, 4)
void attn_kernel(const ushort* __restrict__ qc,
                 const ushort* __restrict__ kc,
                 const ushort* __restrict__ vt,
                 const unsigned char* __restrict__ mask,
                 ushort* __restrict__ out)
{
    __shared__ __align__(16) ushort Ks[2][64 * 64];
    __shared__ __align__(16) ushort Vs[2][64 * 64];
    __shared__ __align__(16) ushort Ps[8][16 * 72];

    const int tid  = threadIdx.x;
    const int wid  = tid >> 6;        // 0..7
    const int lane = tid & 63;
    const int c    = lane & 15;
    const int hi   = lane >> 4;

    const int bid = blockIdx.x;
    const int qt = bid & 15;          // 16 q-tiles of 128 rows
    const int h  = (bid >> 4) & 15;
    const int b  = bid >> 8;

    const ushort* qbase = qc + ((size_t)(b * HEADS + h)) * SEQ * HD;
    const ushort* kbase = kc + ((size_t)(b * HEADS + h)) * SEQ * HD;
    const ushort* vbase = vt + ((size_t)(b * HEADS + h)) * HD * SEQ;
    const unsigned char* mbase = mask + b * SEQ;

    // ---- Q fragments (global loads precede STAGE; drained by prologue wait)
    const int qrow = qt * 128 + wid * 16 + c;
    short8 qf[2];
#pragma unroll
    for (int ks = 0; ks < 2; ++ks)
        qf[ks] = *(const short8*)(qbase + (size_t)qrow * HD + ks * 32 + hi * 8);

    float l_r[4] = {0.f, 0.f, 0.f, 0.f};
    float4v o[4];
#pragma unroll
    for (int j = 0; j < 4; j++) o[j] = (float4v)0.f;

    const int lrow8 = lane >> 3;
    const int gc    = (lane & 7) ^ lrow8;   // pre-swizzled global chunk
    ushort* Pw = &Ps[wid][0];

    // ---- stage K/V tile t into buffer sel: wave w stages 8-row group w.
#define STAGE(t, sel)                                                          \
    {                                                                          \
        int row = wid * 8 + lrow8;                                             \
        async_ld16(kbase + (size_t)((t) * 64 + row) * HD + gc * 8,             \
                   &Ks[sel][wid * 512]);                                       \
        async_ld16(vbase + (size_t)row * SEQ + (t) * 64 + gc * 8,              \
                   &Vs[sel][wid * 512]);                                       \
    }

    // prologue: mask bytes for tile 0 + stage tile 0
    uint32_t mcur[4], mnext[4];
#pragma unroll
    for (int j = 0; j < 4; ++j)
        mcur[j] = mbase[j * 16 + c];
    STAGE(0, 0);
    asm volatile("s_waitcnt vmcnt(0)" ::: "memory");
    __syncthreads();

    int cur = 0;
    for (int kt = 0; kt < SEQ / 64; ++kt) {
        // issue next tile's DMA + next tile's mask bytes — all fly during
        // this tile's compute; drained together at the bottom vmcnt(0).
        if (kt + 1 < SEQ / 64) STAGE(kt + 1, cur ^ 1);
        const int tn = (kt + 1 < SEQ / 64) ? kt + 1 : kt;   // clamped
#pragma unroll
        for (int j = 0; j < 4; ++j)
            mnext[j] = mbase[tn * 64 + j * 16 + c];

        const ushort* Kc = &Ks[cur][0];
        const ushort* Vc = &Vs[cur][0];

        // mask additive terms from the regs prefetched LAST iteration
        float mzv[4];
#pragma unroll
        for (int j = 0; j < 4; ++j)
            mzv[j] = mcur[j] ? -1e30f : 0.0f;

        float4v s[4];
        __builtin_amdgcn_s_setprio(1);
#pragma unroll
        for (int j = 0; j < 4; j++) {
            s[j] = (float4v)0.f;
#pragma unroll
            for (int ks = 0; ks < 2; ks++) {
                int row = j * 16 + c;
                int cc  = ks * 4 + hi;
                short8 kf = *(const short8*)&Kc[row * 64 + ((cc ^ (row & 7)) * 8)];
                s[j] = __builtin_amdgcn_mfma_f32_16x16x32_bf16(qf[ks], kf, s[j], 0, 0, 0);
            }
        }
        __builtin_amdgcn_s_setprio(0);

        // exp2 -> accumulate l, write P (C-layout -> A-layout via LDS)
#pragma unroll
        for (int j = 0; j < 4; j++) {
            int prow = (hi << 2) * 72 + j * 16 + c;
#pragma unroll
            for (int r = 0; r < 4; r++) {
                float p = fast_exp2(s[j][r] + mzv[j]);   // 1 add + 1 v_exp
                l_r[r] += p;
                Pw[prow + r * 72] = f2bf_rn(p);          // 2 VALU
            }
        }
        asm volatile("s_waitcnt lgkmcnt(0)" ::: "memory");   // wave-private RAW

        short8 pf[2];
#pragma unroll
        for (int ks = 0; ks < 2; ks++)
            pf[ks] = *(const short8*)&Pw[c * 72 + ks * 32 + hi * 8];

        __builtin_amdgcn_s_setprio(1);
#pragma unroll
        for (int j = 0; j < 4; j++) {
            int d = j * 16 + c;
#pragma unroll
            for (int ks = 0; ks < 2; ks++) {
                int cc = ks * 4 + hi;
                short8 vf = *(const short8*)&Vc[d * 64 + ((cc ^ (d & 7)) * 8)];
                o[j] = __builtin_amdgcn_mfma_f32_16x16x32_bf16(pf[ks], vf, o[j], 0, 0, 0);
            }
        }
        __builtin_amdgcn_s_setprio(0);

        // end of tile: next tile's DMA + mask bytes (issued at top) drain
        // here, after a full compute phase of cover.
        asm volatile("s_waitcnt vmcnt(0)" ::: "memory");
        __syncthreads();
        cur ^= 1;
#pragma unroll
        for (int j = 0; j < 4; ++j)
            mcur[j] = mnext[j];
    }
#undef STAGE

#pragma unroll
    for (int r = 0; r < 4; r++)
#pragma unroll
        for (int off = 1; off < 16; off <<= 1)
            l_r[r] += __shfl_xor(l_r[r], off, 64);

    const int qrow_out = qt * 128 + wid * 16 + (hi << 2);
#pragma unroll
    for (int j = 0; j < 4; j++) {
        int d = j * 16 + c;
#pragma unroll
        for (int r = 0; r < 4; r++) {
            float val = o[j][r] / l_r[r];
            out[((size_t)(b * SEQ + qrow_out + r)) * EMB + h * HD + d] = f2bf(val);
        }
    }
}

// ---------------------------------------------------------------------------
extern "C" void kernel_launch(void* const* d_in, const int* in_sizes, int n_in,
                              void* d_out, int out_size, void* d_ws, size_t ws_size,
                              hipStream_t stream)
{
    const float* query = (const float*)d_in[0];
    const float* key_  = (const float*)d_in[1];
    const float* value = (const float*)d_in[2];
    const unsigned char* mask = (const unsigned char*)d_in[3];
    const float* Wq  = (const float*)d_in[4];
    const float* bq  = (const float*)d_in[5];
    const float* Wk  = (const float*)d_in[6];
    const float* bk  = (const float*)d_in[7];
    const float* Wv  = (const float*)d_in[8];
    const float* bv  = (const float*)d_in[9];
    const float* Wo  = (const float*)d_in[10];
    const float* bo  = (const float*)d_in[11];
    const float* cbq = (const float*)d_in[12];
    const float* cbk = (const float*)d_in[13];

    ushort* ws = (ushort*)d_ws;
    const size_t n1 = (size_t)BT * EMB;   // 4M elems
    const size_t nw = (size_t)EMB * EMB;  // 1M elems
    ushort* qb  = ws;
    ushort* kb  = qb  + n1;
    ushort* vb  = kb  + n1;
    ushort* wqb = vb  + n1;
    ushort* wkb = wqb + nw;
    ushort* wvb = wkb + nw;
    ushort* wob = wvb + nw;
    ushort* qc  = wob + nw;           // (B,H,T,D) centered, *log2e/8
    ushort* kc  = qc  + n1;           // (B,H,T,D) centered
    ushort* vt  = kc  + n1;           // (B,H,D,T)
    ushort* ao  = qb;                 // reuse qb slot (stream-serialized)

    cvt_all<<<8192, 256, 0, stream>>>(query, key_, value, Wq, Wk, Wv, Wo,
                                      qb, kb, vb, wqb, wkb, wvb, wob);

    dim3 gq(EMB / 128, BT / 128, 3);
    gemm_qkv<<<gq, 256, 0, stream>>>(qb, kb, vb, wqb, wkb, wvb,
                                     bq, bk, bv, cbq, cbk, qc, kc, vt);

    attn_kernel<<<BATCH * HEADS * (SEQ / 128), 512, 0, stream>>>(qc, kc, vt, mask, ao);

    dim3 go(EMB / 64, BT / 64);
    gemm_out<<<go, 256, 0, stream>>>(ao, wob, bo, (float*)d_out);
}

// Round 14
// 229.883 us; speedup vs baseline: 1.0308x; 1.0130x over previous
//
#include <hip/hip_runtime.h>
#include <stdint.h>

static constexpr int EMB   = 1024;
static constexpr int HEADS = 16;
static constexpr int HD    = 64;
static constexpr int BATCH = 2;
static constexpr int SEQ   = 2048;
static constexpr int BT    = BATCH * SEQ;   // 4096 rows
static constexpr float QSC = 0.18033688011112042f;  // log2(e)/8

typedef short   short8  __attribute__((ext_vector_type(8)));
typedef float   float4v __attribute__((ext_vector_type(4)));

__device__ __forceinline__ ushort f2bf(float f) {          // RNE (epilogues)
    union { float f; uint32_t i; } v; v.f = f;
    uint32_t x = v.i;
    return (ushort)((x + 0x7FFFu + ((x >> 16) & 1u)) >> 16);
}
__device__ __forceinline__ ushort f2bf_rn(float f) {       // round-half-up, 2 VALU
    union { float f; uint32_t i; } v; v.f = f;
    return (ushort)((v.i + 0x8000u) >> 16);
}
__device__ __forceinline__ uint32_t pack2bf(float lo, float hi) {
    union { float f; uint32_t u; } a, b; a.f = lo; b.f = hi;
    uint32_t ra = a.u + 0x7FFFu + ((a.u >> 16) & 1u);
    uint32_t rb = b.u + 0x7FFFu + ((b.u >> 16) & 1u);
    return (rb & 0xFFFF0000u) | (ra >> 16);
}
__device__ __forceinline__ float fast_exp2(float x) {
#if __has_builtin(__builtin_amdgcn_exp2f)
    return __builtin_amdgcn_exp2f(x);   // raw v_exp_f32: 1 instr, -1e30 -> 0
#else
    return exp2f(x);
#endif
}

// async 16B global->LDS (DMA). LDS dest = wave-uniform base + lane*16.
__device__ __forceinline__ void async_ld16(const void* g, void* l) {
    __builtin_amdgcn_global_load_lds(
        (const __attribute__((address_space(1))) void*)g,
        (__attribute__((address_space(3))) void*)l,
        16, 0, 0);
}

// ---------------------------------------------------------------------------
// Pre-pass: convert fp32 inputs -> bf16 workspace. 8 elems/thread.
// ---------------------------------------------------------------------------
__global__ void cvt_all(const float* __restrict__ q, const float* __restrict__ k,
                        const float* __restrict__ v,
                        const float* __restrict__ wq, const float* __restrict__ wk,
                        const float* __restrict__ wv, const float* __restrict__ wo,
                        ushort* __restrict__ qb, ushort* __restrict__ kb,
                        ushort* __restrict__ vb,
                        ushort* __restrict__ wqb, ushort* __restrict__ wkb,
                        ushort* __restrict__ wvb, ushort* __restrict__ wob)
{
    int bid = blockIdx.x;
    const float* src; ushort* dst; size_t off;
    if (bid < 6144) {
        int seg = bid >> 11;
        src = seg == 0 ? q : (seg == 1 ? k : v);
        dst = seg == 0 ? qb : (seg == 1 ? kb : vb);
        off = (size_t)(bid & 2047) * 2048;
    } else {
        int t = bid - 6144, seg = t >> 9;
        src = seg == 0 ? wq : (seg == 1 ? wk : (seg == 2 ? wv : wo));
        dst = seg == 0 ? wqb : (seg == 1 ? wkb : (seg == 2 ? wvb : wob));
        off = (size_t)(t & 511) * 2048;
    }
    size_t base = off + (size_t)threadIdx.x * 8;
    float4 a0 = *(const float4*)(src + base);
    float4 a1 = *(const float4*)(src + base + 4);
    uint32_t o[4] = { pack2bf(a0.x, a0.y), pack2bf(a0.z, a0.w),
                      pack2bf(a1.x, a1.y), pack2bf(a1.z, a1.w) };
    *(uint4*)(dst + base) = *(uint4*)o;
}

// ---------------------------------------------------------------------------
// Core 128x128 GEMM tile (m97 structure): 4 waves, each 64x64 = 4x4 MFMA acc.
// DRAIN staging (round-12/13 A/B: at >=3 blocks/CU the implicit wave-level
// overlap of 12+ waves/CU hides the barrier drain; pipelined dbuf measured
// WORSE in both GEMMs — occupancy/slack beats prefetch here).
// Swizzled global_load_lds: LDS(rowgroup, lane) holds chunk (lane&7)^(row&7).
// ---------------------------------------------------------------------------
__device__ __forceinline__ void gemm_core_128(
    const ushort* __restrict__ A, const ushort* __restrict__ W,
    int m0, int n0, int K,
    ushort* As, ushort* Ws,
    int wid, int lane, float4v acc[4][4])
{
    const int lrow8 = lane >> 3;
    const int gc    = (lane & 7) ^ lrow8;
    const ushort* Ab = A + (size_t)m0 * K + gc * 8;
    const ushort* Wb = W + (size_t)n0 * K + gc * 8;
    const int wm = (wid >> 1) * 64;
    const int wn = (wid & 1) * 64;

    for (int k0 = 0; k0 < K; k0 += 64) {
        __syncthreads();
#pragma unroll
        for (int it = 0; it < 4; ++it) {
            int rg = it * 4 + wid;               // row group 0..15 (8 rows each)
            int row = rg * 8 + lrow8;
            async_ld16(Ab + (size_t)row * K + k0, &As[rg * 512]);
            async_ld16(Wb + (size_t)row * K + k0, &Ws[rg * 512]);
        }
        __syncthreads();
#pragma unroll
        for (int ks = 0; ks < 2; ++ks) {
            const int c = ks * 4 + (lane >> 4);
            short8 af[4], wf[4];
#pragma unroll
            for (int i = 0; i < 4; i++) {
                int row = wm + i * 16 + (lane & 15);
                af[i] = *(const short8*)&As[row * 64 + ((c ^ (row & 7)) * 8)];
            }
#pragma unroll
            for (int j = 0; j < 4; j++) {
                int row = wn + j * 16 + (lane & 15);
                wf[j] = *(const short8*)&Ws[row * 64 + ((c ^ (row & 7)) * 8)];
            }
#pragma unroll
            for (int i = 0; i < 4; i++)
#pragma unroll
                for (int j = 0; j < 4; j++)
                    acc[i][j] = __builtin_amdgcn_mfma_f32_16x16x32_bf16(af[i], wf[j], acc[i][j], 0, 0, 0);
        }
    }
}

// ---------------------------------------------------------------------------
// Fused Q/K/V projection GEMM: blockIdx.z selects {Q,K,V}. Drain core,
// 32 KB LDS -> 3 blocks/CU (round-12 A/B winner).
// v13: XCD panel-locality swizzle — grid is now (m-tiles, n-tiles, z) so
// linear id % 8 = m-tile % 8: the 8 blocks sharing an A-panel co-locate on
// one XCD (A fetched 1x/XCD instead of 8x); W panels (smaller) spread.
// ---------------------------------------------------------------------------
__global__ __launch_bounds__(256, 3)
void gemm_qkv(const ushort* __restrict__ qb, const ushort* __restrict__ kb,
              const ushort* __restrict__ vb,
              const ushort* __restrict__ wqb, const ushort* __restrict__ wkb,
              const ushort* __restrict__ wvb,
              const float* __restrict__ bq, const float* __restrict__ bk,
              const float* __restrict__ bv,
              const float* __restrict__ cbq, const float* __restrict__ cbk,
              ushort* __restrict__ qc, ushort* __restrict__ kc,
              ushort* __restrict__ vt)
{
    __shared__ __align__(16) ushort As[128 * 64];
    __shared__ __align__(16) ushort Ws[128 * 64];

    const int z = blockIdx.z;
    const ushort* A    = z == 0 ? qb  : (z == 1 ? kb  : vb);
    const ushort* W    = z == 0 ? wqb : (z == 1 ? wkb : wvb);
    const float*  bias = z == 0 ? bq  : (z == 1 ? bk  : bv);
    const float*  clrb = z == 0 ? cbq : cbk;
    const float   scale = z == 0 ? QSC : 1.0f;

    const int tid  = threadIdx.x;
    const int wid  = tid >> 6;
    const int lane = tid & 63;
    const int m0 = blockIdx.x * 128;   // m from x: id%8 = m%8 -> A-panel/XCD
    const int n0 = blockIdx.y * 128;
    const int wm = (wid >> 1) * 64;
    const int wn = (wid & 1) * 64;

    float4v acc[4][4];
#pragma unroll
    for (int i = 0; i < 4; i++)
#pragma unroll
        for (int j = 0; j < 4; j++) acc[i][j] = (float4v)0.0f;

    gemm_core_128(A, W, m0, n0, EMB, As, Ws, wid, lane, acc);

    // Epilogue. C/D: col=lane&15, row=(lane>>4)*4+reg  [m89]
    const int h = (n0 + wn) >> 6;   // head (64 cols == wave n-tile)
#pragma unroll
    for (int i = 0; i < 4; i++) {
        float ys[4][4];
#pragma unroll
        for (int j = 0; j < 4; j++) {
            float bj = bias[n0 + wn + j * 16 + (lane & 15)];
#pragma unroll
            for (int r = 0; r < 4; r++) ys[j][r] = acc[i][j][r] + bj;
        }
        const int rowb = m0 + wm + i * 16 + ((lane >> 4) << 2);

        if (z < 2) {
            float rs[4];
#pragma unroll
            for (int r = 0; r < 4; r++)
                rs[r] = ys[0][r] + ys[1][r] + ys[2][r] + ys[3][r];
#pragma unroll
            for (int r = 0; r < 4; r++)
#pragma unroll
                for (int off = 1; off < 16; off <<= 1)
                    rs[r] += __shfl_xor(rs[r], off, 64);
            ushort* Yb = z == 0 ? qc : kc;
#pragma unroll
            for (int j = 0; j < 4; j++) {
                int d = j * 16 + (lane & 15);
                float cb = clrb[h * HD + d];
#pragma unroll
                for (int r = 0; r < 4; r++) {
                    int row = rowb + r;
                    int b = row >> 11, t = row & (SEQ - 1);
                    Yb[((size_t)(b * HEADS + h) * SEQ + t) * HD + d] =
                        f2bf((ys[j][r] - rs[r] * (1.0f / 64.0f) + cb) * scale);
                }
            }
        } else {
#pragma unroll
            for (int j = 0; j < 4; j++) {
                int d = j * 16 + (lane & 15);
#pragma unroll
                for (int r = 0; r < 4; r++) {
                    int row = rowb + r;
                    int b = row >> 11, t = row & (SEQ - 1);
                    vt[((size_t)(b * HEADS + h) * HD + d) * SEQ + t] = f2bf(ys[j][r]);
                }
            }
        }
    }
}

// ---------------------------------------------------------------------------
// Output projection GEMM: fp32 row-major output. 64x64 tiles, 4 blocks/CU.
// v13: reverted to DRAIN staging (R13 A/B: pipelined dbuf cost ~+2.5 µs) and
// XCD panel-locality swizzle: grid (m-tiles, n-tiles) so id%8 = m%8 — the 16
// blocks sharing an ao A-panel co-locate per XCD.
// ---------------------------------------------------------------------------
__global__ __launch_bounds__(256, 4)
void gemm_out(const ushort* __restrict__ A, const ushort* __restrict__ W,
              const float* __restrict__ bias, float* __restrict__ Y)
{
    __shared__ __align__(16) ushort As[64 * 64];
    __shared__ __align__(16) ushort Ws[64 * 64];

    const int tid  = threadIdx.x;
    const int wid  = tid >> 6;
    const int lane = tid & 63;
    const int m0 = blockIdx.x * 64;    // m from x: id%8 = m%8 -> A-panel/XCD
    const int n0 = blockIdx.y * 64;
    const int wm = (wid >> 1) * 32;
    const int wn = (wid & 1) * 32;

    const int lrow8 = lane >> 3;
    const int gc    = (lane & 7) ^ lrow8;
    const ushort* Ab = A + (size_t)m0 * EMB + gc * 8;
    const ushort* Wb = W + (size_t)n0 * EMB + gc * 8;

    float4v acc[2][2];
#pragma unroll
    for (int i = 0; i < 2; i++)
#pragma unroll
        for (int j = 0; j < 2; j++) acc[i][j] = (float4v)0.0f;

    for (int k0 = 0; k0 < EMB; k0 += 64) {
        __syncthreads();
#pragma unroll
        for (int it = 0; it < 2; ++it) {
            int rg = it * 4 + wid;               // row group 0..7 (8 rows each)
            int row = rg * 8 + lrow8;
            async_ld16(Ab + (size_t)row * EMB + k0, &As[rg * 512]);
            async_ld16(Wb + (size_t)row * EMB + k0, &Ws[rg * 512]);
        }
        __syncthreads();
#pragma unroll
        for (int ks = 0; ks < 2; ++ks) {
            const int c = ks * 4 + (lane >> 4);
            short8 af[2], wf[2];
#pragma unroll
            for (int i = 0; i < 2; i++) {
                int row = wm + i * 16 + (lane & 15);
                af[i] = *(const short8*)&As[row * 64 + ((c ^ (row & 7)) * 8)];
            }
#pragma unroll
            for (int j = 0; j < 2; j++) {
                int row = wn + j * 16 + (lane & 15);
                wf[j] = *(const short8*)&Ws[row * 64 + ((c ^ (row & 7)) * 8)];
            }
#pragma unroll
            for (int i = 0; i < 2; i++)
#pragma unroll
                for (int j = 0; j < 2; j++)
                    acc[i][j] = __builtin_amdgcn_mfma_f32_16x16x32_bf16(af[i], wf[j], acc[i][j], 0, 0, 0);
        }
    }

#pragma unroll
    for (int i = 0; i < 2; i++) {
        const int rowb = m0 + wm + i * 16 + ((lane >> 4) << 2);
#pragma unroll
        for (int j = 0; j < 2; j++) {
            int col = n0 + wn + j * 16 + (lane & 15);
            float bj = bias[col];
#pragma unroll
            for (int r = 0; r < 4; r++)
                Y[(size_t)(rowb + r) * EMB + col] = acc[i][j][r] + bj;
        }
    }
}

// ---------------------------------------------------------------------------
// Flash attention, static softmax (scores provably small; Q pre-scaled by
// log2(e)/8 -> p=exp2(s), m==0). Per (b,h,128-q-tile), KVBLK=64 dbuf.
// v10 structure unchanged (best measured: 63.2-63.9 µs): 8 waves x 16 q-rows,
// mask-in-registers (vmcnt-clean prefetch in the STAGE window), LDS 51200 B.
// ---------------------------------------------------------------------------
__global__ __launch_bounds__(512, 4)
void attn_kernel(const ushort* __restrict__ qc,
                 const ushort* __restrict__ kc,
                 const ushort* __restrict__ vt,
                 const unsigned char* __restrict__ mask,
                 ushort* __restrict__ out)
{
    __shared__ __align__(16) ushort Ks[2][64 * 64];
    __shared__ __align__(16) ushort Vs[2][64 * 64];
    __shared__ __align__(16) ushort Ps[8][16 * 72];

    const int tid  = threadIdx.x;
    const int wid  = tid >> 6;        // 0..7
    const int lane = tid & 63;
    const int c    = lane & 15;
    const int hi   = lane >> 4;

    const int bid = blockIdx.x;
    const int qt = bid & 15;          // 16 q-tiles of 128 rows
    const int h  = (bid >> 4) & 15;
    const int b  = bid >> 8;

    const ushort* qbase = qc + ((size_t)(b * HEADS + h)) * SEQ * HD;
    const ushort* kbase = kc + ((size_t)(b * HEADS + h)) * SEQ * HD;
    const ushort* vbase = vt + ((size_t)(b * HEADS + h)) * HD * SEQ;
    const unsigned char* mbase = mask + b * SEQ;

    // ---- Q fragments (global loads precede STAGE; drained by prologue wait)
    const int qrow = qt * 128 + wid * 16 + c;
    short8 qf[2];
#pragma unroll
    for (int ks = 0; ks < 2; ++ks)
        qf[ks] = *(const short8*)(qbase + (size_t)qrow * HD + ks * 32 + hi * 8);

    float l_r[4] = {0.f, 0.f, 0.f, 0.f};
    float4v o[4];
#pragma unroll
    for (int j = 0; j < 4; j++) o[j] = (float4v)0.f;

    const int lrow8 = lane >> 3;
    const int gc    = (lane & 7) ^ lrow8;   // pre-swizzled global chunk
    ushort* Pw = &Ps[wid][0];

    // ---- stage K/V tile t into buffer sel: wave w stages 8-row group w.
#define STAGE(t, sel)                                                          \
    {                                                                          \
        int row = wid * 8 + lrow8;                                             \
        async_ld16(kbase + (size_t)((t) * 64 + row) * HD + gc * 8,             \
                   &Ks[sel][wid * 512]);                                       \
        async_ld16(vbase + (size_t)row * SEQ + (t) * 64 + gc * 8,              \
                   &Vs[sel][wid * 512]);                                       \
    }

    // prologue: mask bytes for tile 0 + stage tile 0
    uint32_t mcur[4], mnext[4];
#pragma unroll
    for (int j = 0; j < 4; ++j)
        mcur[j] = mbase[j * 16 + c];
    STAGE(0, 0);
    asm volatile("s_waitcnt vmcnt(0)" ::: "memory");
    __syncthreads();

    int cur = 0;
    for (int kt = 0; kt < SEQ / 64; ++kt) {
        // issue next tile's DMA + next tile's mask bytes — all fly during
        // this tile's compute; drained together at the bottom vmcnt(0).
        if (kt + 1 < SEQ / 64) STAGE(kt + 1, cur ^ 1);
        const int tn = (kt + 1 < SEQ / 64) ? kt + 1 : kt;   // clamped
#pragma unroll
        for (int j = 0; j < 4; ++j)
            mnext[j] = mbase[tn * 64 + j * 16 + c];

        const ushort* Kc = &Ks[cur][0];
        const ushort* Vc = &Vs[cur][0];

        // mask additive terms from the regs prefetched LAST iteration
        float mzv[4];
#pragma unroll
        for (int j = 0; j < 4; ++j)
            mzv[j] = mcur[j] ? -1e30f : 0.0f;

        float4v s[4];
        __builtin_amdgcn_s_setprio(1);
#pragma unroll
        for (int j = 0; j < 4; j++) {
            s[j] = (float4v)0.f;
#pragma unroll
            for (int ks = 0; ks < 2; ks++) {
                int row = j * 16 + c;
                int cc  = ks * 4 + hi;
                short8 kf = *(const short8*)&Kc[row * 64 + ((cc ^ (row & 7)) * 8)];
                s[j] = __builtin_amdgcn_mfma_f32_16x16x32_bf16(qf[ks], kf, s[j], 0, 0, 0);
            }
        }
        __builtin_amdgcn_s_setprio(0);

        // exp2 -> accumulate l, write P (C-layout -> A-layout via LDS)
#pragma unroll
        for (int j = 0; j < 4; j++) {
            int prow = (hi << 2) * 72 + j * 16 + c;
#pragma unroll
            for (int r = 0; r < 4; r++) {
                float p = fast_exp2(s[j][r] + mzv[j]);   // 1 add + 1 v_exp
                l_r[r] += p;
                Pw[prow + r * 72] = f2bf_rn(p);          // 2 VALU
            }
        }
        asm volatile("s_waitcnt lgkmcnt(0)" ::: "memory");   // wave-private RAW

        short8 pf[2];
#pragma unroll
        for (int ks = 0; ks < 2; ks++)
            pf[ks] = *(const short8*)&Pw[c * 72 + ks * 32 + hi * 8];

        __builtin_amdgcn_s_setprio(1);
#pragma unroll
        for (int j = 0; j < 4; j++) {
            int d = j * 16 + c;
#pragma unroll
            for (int ks = 0; ks < 2; ks++) {
                int cc = ks * 4 + hi;
                short8 vf = *(const short8*)&Vc[d * 64 + ((cc ^ (d & 7)) * 8)];
                o[j] = __builtin_amdgcn_mfma_f32_16x16x32_bf16(pf[ks], vf, o[j], 0, 0, 0);
            }
        }
        __builtin_amdgcn_s_setprio(0);

        // end of tile: next tile's DMA + mask bytes (issued at top) drain
        // here, after a full compute phase of cover.
        asm volatile("s_waitcnt vmcnt(0)" ::: "memory");
        __syncthreads();
        cur ^= 1;
#pragma unroll
        for (int j = 0; j < 4; ++j)
            mcur[j] = mnext[j];
    }
#undef STAGE

#pragma unroll
    for (int r = 0; r < 4; r++)
#pragma unroll
        for (int off = 1; off < 16; off <<= 1)
            l_r[r] += __shfl_xor(l_r[r], off, 64);

    const int qrow_out = qt * 128 + wid * 16 + (hi << 2);
#pragma unroll
    for (int j = 0; j < 4; j++) {
        int d = j * 16 + c;
#pragma unroll
        for (int r = 0; r < 4; r++) {
            float val = o[j][r] / l_r[r];
            out[((size_t)(b * SEQ + qrow_out + r)) * EMB + h * HD + d] = f2bf(val);
        }
    }
}

// ---------------------------------------------------------------------------
extern "C" void kernel_launch(void* const* d_in, const int* in_sizes, int n_in,
                              void* d_out, int out_size, void* d_ws, size_t ws_size,
                              hipStream_t stream)
{
    const float* query = (const float*)d_in[0];
    const float* key_  = (const float*)d_in[1];
    const float* value = (const float*)d_in[2];
    const unsigned char* mask = (const unsigned char*)d_in[3];
    const float* Wq  = (const float*)d_in[4];
    const float* bq  = (const float*)d_in[5];
    const float* Wk  = (const float*)d_in[6];
    const float* bk  = (const float*)d_in[7];
    const float* Wv  = (const float*)d_in[8];
    const float* bv  = (const float*)d_in[9];
    const float* Wo  = (const float*)d_in[10];
    const float* bo  = (const float*)d_in[11];
    const float* cbq = (const float*)d_in[12];
    const float* cbk = (const float*)d_in[13];

    ushort* ws = (ushort*)d_ws;
    const size_t n1 = (size_t)BT * EMB;   // 4M elems
    const size_t nw = (size_t)EMB * EMB;  // 1M elems
    ushort* qb  = ws;
    ushort* kb  = qb  + n1;
    ushort* vb  = kb  + n1;
    ushort* wqb = vb  + n1;
    ushort* wkb = wqb + nw;
    ushort* wvb = wkb + nw;
    ushort* wob = wvb + nw;
    ushort* qc  = wob + nw;           // (B,H,T,D) centered, *log2e/8
    ushort* kc  = qc  + n1;           // (B,H,T,D) centered
    ushort* vt  = kc  + n1;           // (B,H,D,T)
    ushort* ao  = qb;                 // reuse qb slot (stream-serialized)

    cvt_all<<<8192, 256, 0, stream>>>(query, key_, value, Wq, Wk, Wv, Wo,
                                      qb, kb, vb, wqb, wkb, wvb, wob);

    dim3 gq(BT / 128, EMB / 128, 3);   // (m, n, z): id%8 = m%8 -> A-panel/XCD
    gemm_qkv<<<gq, 256, 0, stream>>>(qb, kb, vb, wqb, wkb, wvb,
                                     bq, bk, bv, cbq, cbk, qc, kc, vt);

    attn_kernel<<<BATCH * HEADS * (SEQ / 128), 512, 0, stream>>>(qc, kc, vt, mask, ao);

    dim3 go(BT / 64, EMB / 64);        // (m, n): id%8 = m%8 -> A-panel/XCD
    gemm_out<<<go, 256, 0, stream>>>(ao, wob, bo, (float*)d_out);
}